// Round 9
// baseline (359.106 us; speedup 1.0000x reference)
//
#include <hip/hip_runtime.h>
#include <math.h>

// Problem constants (fixed by the reference)
#define T_    1024      // B*S tokens
#define H_    512       // hidden
#define I_    1024      // intermediate
#define E_    64        // routed experts
#define K_    4         // top-k
#define NPAIR (T_*K_)   // 4096 routed (token,slot) pairs
#define NENT  (NPAIR + T_)  // + shared-expert entries at [NPAIR + t]

#define BM 128          // rows per work block
#define BN 64           // output cols per block (4 waves x 16)
#define BKS 32          // k-step (elements)
#define MAXWORK 160
#define NT1 (H_/BKS)    // 16
#define NT2 (I_/BKS)    // 32

typedef float  f32x4  __attribute__((ext_vector_type(4)));
typedef short  bf16x8 __attribute__((ext_vector_type(8)));

__device__ __forceinline__ ushort f2bf(float f) {
    uint u = __float_as_uint(f);
    u += 0x7fffu + ((u >> 16) & 1u);   // round-to-nearest-even
    return (ushort)(u >> 16);
}
// packed f32->bf16 (RNE, same as f2bf) - 1 VALU op per 2 elements
__device__ __forceinline__ bf16x8 cvt8pk(f32x4 a, f32x4 b) {
    union { uint u[4]; bf16x8 v; } r;
    asm("v_cvt_pk_bf16_f32 %0, %1, %2" : "=v"(r.u[0]) : "v"(a[0]), "v"(a[1]));
    asm("v_cvt_pk_bf16_f32 %0, %1, %2" : "=v"(r.u[1]) : "v"(a[2]), "v"(a[3]));
    asm("v_cvt_pk_bf16_f32 %0, %1, %2" : "=v"(r.u[2]) : "v"(b[0]), "v"(b[1]));
    asm("v_cvt_pk_bf16_f32 %0, %1, %2" : "=v"(r.u[3]) : "v"(b[2]), "v"(b[3]));
    return r.v;
}

// ---------------------------------------------------------------------------
// x -> bf16 pre-pass (2 MB, ~2 us); makes A-fragment loads 16B bf16 direct.
// ---------------------------------------------------------------------------
__global__ __launch_bounds__(256) void x_cvt(const float* __restrict__ x,
                                             ushort* __restrict__ xb)
{
    const int i = blockIdx.x*256 + threadIdx.x;     // T_*H_/4 float4s
    float4 v = reinterpret_cast<const float4*>(x)[i];
    reinterpret_cast<ushort4*>(xb)[i] =
        make_ushort4(f2bf(v.x), f2bf(v.y), f2bf(v.z), f2bf(v.w));
}

// ---------------------------------------------------------------------------
// Router: one 64-thread block per token.
// ---------------------------------------------------------------------------
__global__ __launch_bounds__(64) void moe_router(
    const float* __restrict__ x, const float* __restrict__ rw,
    const float* __restrict__ rb, const float* __restrict__ eb,
    int* __restrict__ idx_out, float* __restrict__ gate_out)
{
    const int t = blockIdx.x;
    const int lane = threadIdx.x;  // 0..63
    __shared__ float xs[H_];
    __shared__ float lg[E_];
    __shared__ float bs[E_];
    for (int i = lane; i < H_; i += 64) xs[i] = x[(size_t)t*H_ + i];
    bs[lane] = eb[lane];
    __syncthreads();
    float acc = 0.f;
    const float* wrow = rw + (size_t)lane*H_;
    for (int k = 0; k < H_; k += 4) {
        float4 w4 = *reinterpret_cast<const float4*>(wrow + k);
        acc = fmaf(xs[k+0], w4.x, acc);
        acc = fmaf(xs[k+1], w4.y, acc);
        acc = fmaf(xs[k+2], w4.z, acc);
        acc = fmaf(xs[k+3], w4.w, acc);
    }
    lg[lane] = acc + rb[lane];
    __syncthreads();
    if (lane == 0) {
        unsigned long long used = 0ull;
        int sel[K_]; float orig[K_];
        for (int k = 0; k < K_; ++k) {
            float best = -INFINITY; int bi = 0;
            for (int e = 0; e < E_; ++e) {
                if (used & (1ull << e)) continue;
                float v = lg[e] + bs[e];
                if (v > best) { best = v; bi = e; }   // strict > : lowest idx on tie
            }
            used |= (1ull << bi);
            sel[k] = bi; orig[k] = lg[bi];
        }
        float s[K_]; float sum = 0.f;
        for (int k = 0; k < K_; ++k) { s[k] = 1.f/(1.f + __expf(-orig[k])); sum += s[k]; }
        sum = fmaxf(sum, 1e-12f);
        for (int k = 0; k < K_; ++k) {
            idx_out[t*K_ + k] = sel[k];
            gate_out[t*K_ + k] = s[k] / sum;
        }
    }
}

// ---------------------------------------------------------------------------
// Build per-expert token lists + flattened row-block work list (single block).
// ---------------------------------------------------------------------------
__global__ __launch_bounds__(256) void moe_build(
    const int* __restrict__ idx, const float* __restrict__ gates,
    int* __restrict__ cnts, int* __restrict__ offs,
    int* __restrict__ entry_token, float* __restrict__ entry_gate,
    int* __restrict__ pair_pos,
    int* __restrict__ blk_e, int* __restrict__ blk_ro, int* __restrict__ nwork)
{
    __shared__ int c[E_];
    __shared__ int run[E_];
    const int tid = threadIdx.x;
    if (tid < E_) c[tid] = 0;
    __syncthreads();
    for (int p = tid; p < NPAIR; p += 256) atomicAdd(&c[idx[p]], 1);
    __syncthreads();
    if (tid == 0) {
        int o = 0;
        for (int e = 0; e < E_; ++e) { run[e] = o; offs[e] = o; cnts[e] = c[e]; o += c[e]; }
        offs[E_] = NPAIR;   // shared-expert entries
        cnts[E_] = T_;
        int nb = 0;
        for (int e = 0; e <= E_; ++e) {
            int n = (e < E_) ? c[e] : T_;
            for (int ro = 0; ro < n; ro += BM) { blk_e[nb] = e; blk_ro[nb] = ro; ++nb; }
        }
        nwork[0] = nb;
    }
    __syncthreads();
    for (int p = tid; p < NPAIR; p += 256) {
        int e = idx[p];
        int pos = atomicAdd(&run[e], 1);
        entry_token[pos] = p / K_;
        entry_gate[pos]  = gates[p];
        pair_pos[p]      = pos;
    }
    for (int t = tid; t < T_; t += 256) {
        entry_token[NPAIR + t] = t;
        entry_gate[NPAIR + t]  = 1.0f;
    }
}

// ---------------------------------------------------------------------------
// Stage 1: h1 = silu(X w1^T + b1) * (X w3^T + b3) -> bf16
// LDS-FREE, BARRIER-FREE: each wave owns a 128x16 output strip. A-frags
// (bf16 X, L2-hot) and B-frags (fp32 weights, HBM stream) loaded direct to
// registers; W prefetched 1 K-step ahead in named sets; A-loads issued
// before the W prefetch so their dep-wait is counted vmcnt (W stays in
// flight). Full unroll -> all loads are base+imm (max 2048B), zero addr math.
// ---------------------------------------------------------------------------
__global__ __launch_bounds__(256, 2) void moe_stage1(
    const ushort* __restrict__ xbf,
    const float* __restrict__ w1, const float* __restrict__ b1,
    const float* __restrict__ w3, const float* __restrict__ b3,
    const float* __restrict__ sw1, const float* __restrict__ sb1,
    const float* __restrict__ sw3, const float* __restrict__ sb3,
    const int* __restrict__ cnts, const int* __restrict__ offs,
    const int* __restrict__ entry_token,
    const int* __restrict__ blk_e, const int* __restrict__ blk_ro,
    const int* __restrict__ nwork,
    ushort* __restrict__ h1buf)
{
    const int w = blockIdx.x;
    if (w >= nwork[0]) return;
    const int e  = blk_e[w];
    const int ro = blk_ro[w];
    const int itile = blockIdx.y;   // 0..I_/BN-1
    const int n = cnts[e];
    const int off = offs[e];
    const int rows = min(BM, n - ro);
    const float* W1 = (e < E_) ? (w1 + (size_t)e*I_*H_) : sw1;
    const float* W3 = (e < E_) ? (w3 + (size_t)e*I_*H_) : sw3;
    const float* B1 = (e < E_) ? (b1 + (size_t)e*I_) : sb1;
    const float* B3 = (e < E_) ? (b3 + (size_t)e*I_) : sb3;

    const int tid  = threadIdx.x;
    const int lane = tid & 63;
    const int wid  = tid >> 6;      // 0..3: owns cols [wid*16, wid*16+16)
    const int l15  = lane & 15;
    const int lg   = lane >> 4;     // 0..3

    // A-frag bases: 8 M-frags; lane reads X[tok(m*16+l15)][kc + lg*8 ..+7]
    // Rows beyond 'rows' read a neighboring valid entry (entries partition
    // [0,NENT) with no gaps); garbage lands only in masked output rows.
    const ushort* ab[8];
    #pragma unroll
    for (int m = 0; m < 8; ++m) {
        const int tok = entry_token[off + ro + m*16 + l15];
        ab[m] = xbf + (size_t)tok*H_ + lg*8;
    }
    // B-frag bases: lane owns weight row ncol; reads [kc + lg*8 ..+7] fp32
    const int ncol = itile*BN + wid*16 + l15;
    const float* b1p = W1 + (size_t)ncol*H_ + lg*8;
    const float* b3p = W3 + (size_t)ncol*H_ + lg*8;

    f32x4 acc1[8] = {};
    f32x4 acc3[8] = {};

    f32x4 s0[4], s1[4];   // W prefetch sets: [w1lo, w1hi, w3lo, w3hi]

    #define LW1(S, kc) do {                                      \
        S[0] = *reinterpret_cast<const f32x4*>(b1p + (kc));      \
        S[1] = *reinterpret_cast<const f32x4*>(b1p + (kc) + 4);  \
        S[2] = *reinterpret_cast<const f32x4*>(b3p + (kc));      \
        S[3] = *reinterpret_cast<const f32x4*>(b3p + (kc) + 4);  \
    } while (0)

    LW1(s0, 0);
    #pragma unroll
    for (int t = 0; t < NT1; ++t) {
        const int kc = t*BKS;
        // A-loads first: their dep-wait leaves the younger W prefetch in flight
        bf16x8 a[8];
        #pragma unroll
        for (int m = 0; m < 8; ++m)
            a[m] = *reinterpret_cast<const bf16x8*>(ab[m] + kc);
        if (t + 1 < NT1) { if (t & 1) LW1(s0, kc + BKS); else LW1(s1, kc + BKS); }
        bf16x8 f1, f3;
        if (t & 1) { f1 = cvt8pk(s1[0], s1[1]); f3 = cvt8pk(s1[2], s1[3]); }
        else       { f1 = cvt8pk(s0[0], s0[1]); f3 = cvt8pk(s0[2], s0[3]); }
        #pragma unroll
        for (int m = 0; m < 8; ++m) {
            acc1[m] = __builtin_amdgcn_mfma_f32_16x16x32_bf16(a[m], f1, acc1[m], 0, 0, 0);
            acc3[m] = __builtin_amdgcn_mfma_f32_16x16x32_bf16(a[m], f3, acc3[m], 0, 0, 0);
        }
    }
    #undef LW1

    // epilogue: silu(z1)*z3 -> bf16. C/D: row=(lane>>4)*4+j, col=l15 (=ncol)
    const float bv1 = B1[ncol];
    const float bv3 = B3[ncol];
    #pragma unroll
    for (int m = 0; m < 8; ++m) {
        #pragma unroll
        for (int j = 0; j < 4; ++j) {
            const int rl = m*16 + lg*4 + j;
            if (rl < rows) {
                float z1 = acc1[m][j] + bv1;
                float z3 = acc3[m][j] + bv3;
                float h = z1 / (1.f + __expf(-z1)) * z3;
                h1buf[(size_t)(off+ro+rl)*I_ + ncol] = f2bf(h);
            }
        }
    }
}

// ---------------------------------------------------------------------------
// Stage 2: y = gate * (h1 @ w2^T + b2) -> fp32. Same LDS-free template.
// ---------------------------------------------------------------------------
__global__ __launch_bounds__(256, 2) void moe_stage2(
    const ushort* __restrict__ h1buf,
    const float* __restrict__ w2, const float* __restrict__ b2,
    const float* __restrict__ sw2, const float* __restrict__ sb2,
    const int* __restrict__ cnts, const int* __restrict__ offs,
    const float* __restrict__ entry_gate,
    const int* __restrict__ blk_e, const int* __restrict__ blk_ro,
    const int* __restrict__ nwork,
    float* __restrict__ ybuf)
{
    const int w = blockIdx.x;
    if (w >= nwork[0]) return;
    const int e  = blk_e[w];
    const int ro = blk_ro[w];
    const int htile = blockIdx.y;   // 0..H_/BN-1
    const int n = cnts[e];
    const int off = offs[e];
    const int rows = min(BM, n - ro);
    const float* W2 = (e < E_) ? (w2 + (size_t)e*H_*I_) : sw2;
    const float* B2 = (e < E_) ? (b2 + (size_t)e*H_) : sb2;

    const int tid  = threadIdx.x;
    const int lane = tid & 63;
    const int wid  = tid >> 6;      // 0..3
    const int l15  = lane & 15;
    const int lg   = lane >> 4;

    const ushort* ab[8];
    #pragma unroll
    for (int m = 0; m < 8; ++m)
        ab[m] = h1buf + (size_t)(off + ro + m*16 + l15)*I_ + lg*8;
    const int ncol = htile*BN + wid*16 + l15;
    const float* bp = W2 + (size_t)ncol*I_ + lg*8;

    f32x4 acc[8] = {};

    f32x4 s0[2], s1[2];

    #define LW2(S, kc) do {                                     \
        S[0] = *reinterpret_cast<const f32x4*>(bp + (kc));      \
        S[1] = *reinterpret_cast<const f32x4*>(bp + (kc) + 4);  \
    } while (0)

    LW2(s0, 0);
    #pragma unroll
    for (int t = 0; t < NT2; ++t) {
        const int kc = t*BKS;
        bf16x8 a[8];
        #pragma unroll
        for (int m = 0; m < 8; ++m)
            a[m] = *reinterpret_cast<const bf16x8*>(ab[m] + kc);
        if (t + 1 < NT2) { if (t & 1) LW2(s0, kc + BKS); else LW2(s1, kc + BKS); }
        bf16x8 f;
        if (t & 1) f = cvt8pk(s1[0], s1[1]);
        else       f = cvt8pk(s0[0], s0[1]);
        #pragma unroll
        for (int m = 0; m < 8; ++m)
            acc[m] = __builtin_amdgcn_mfma_f32_16x16x32_bf16(a[m], f, acc[m], 0, 0, 0);
    }
    #undef LW2

    const float bv = B2[ncol];
    #pragma unroll
    for (int m = 0; m < 8; ++m) {
        #pragma unroll
        for (int j = 0; j < 4; ++j) {
            const int rl = m*16 + lg*4 + j;
            if (rl < rows) {
                const float g = entry_gate[off + ro + rl];
                ybuf[(size_t)(off+ro+rl)*H_ + ncol] = (acc[m][j] + bv) * g;
            }
        }
    }
}

// ---------------------------------------------------------------------------
// Combine: out[t] = y_shared[t] + sum_k y_routed[pair_pos[t,k]]
// ---------------------------------------------------------------------------
__global__ __launch_bounds__(128) void moe_combine(
    const float* __restrict__ ybuf, const int* __restrict__ pair_pos,
    float* __restrict__ out)
{
    const int t = blockIdx.x;
    const int lane = threadIdx.x;     // 128 threads * 4 floats = 512
    const int h = lane * 4;
    const int p0 = pair_pos[t*K_+0], p1 = pair_pos[t*K_+1];
    const int p2 = pair_pos[t*K_+2], p3 = pair_pos[t*K_+3];
    float4 a  = *reinterpret_cast<const float4*>(ybuf + (size_t)(NPAIR+t)*H_ + h);
    float4 v0 = *reinterpret_cast<const float4*>(ybuf + (size_t)p0*H_ + h);
    float4 v1 = *reinterpret_cast<const float4*>(ybuf + (size_t)p1*H_ + h);
    float4 v2 = *reinterpret_cast<const float4*>(ybuf + (size_t)p2*H_ + h);
    float4 v3 = *reinterpret_cast<const float4*>(ybuf + (size_t)p3*H_ + h);
    float4 r;
    r.x = a.x + v0.x + v1.x + v2.x + v3.x;
    r.y = a.y + v0.y + v1.y + v2.y + v3.y;
    r.z = a.z + v0.z + v1.z + v2.z + v3.z;
    r.w = a.w + v0.w + v1.w + v2.w + v3.w;
    *reinterpret_cast<float4*>(out + (size_t)t*H_ + h) = r;
}

extern "C" void kernel_launch(void* const* d_in, const int* in_sizes, int n_in,
                              void* d_out, int out_size, void* d_ws, size_t ws_size,
                              hipStream_t stream)
{
    const float* x   = (const float*)d_in[0];
    const float* rw  = (const float*)d_in[1];
    const float* rb  = (const float*)d_in[2];
    const float* eb  = (const float*)d_in[3];
    const float* sw1 = (const float*)d_in[4];
    const float* sb1 = (const float*)d_in[5];
    const float* sw2 = (const float*)d_in[6];
    const float* sb2 = (const float*)d_in[7];
    const float* sw3 = (const float*)d_in[8];
    const float* sb3 = (const float*)d_in[9];
    const float* w1  = (const float*)d_in[10];
    const float* b1  = (const float*)d_in[11];
    const float* w2  = (const float*)d_in[12];
    const float* b2  = (const float*)d_in[13];
    const float* w3  = (const float*)d_in[14];
    const float* b3  = (const float*)d_in[15];
    float* out = (float*)d_out;

    char* p = (char*)d_ws;
    auto take = [&](size_t bytes) { char* q = p; p += (bytes + 255) & ~(size_t)255; return q; };
    int*    idxb  = (int*)   take((size_t)NPAIR*4);
    float*  gateb = (float*) take((size_t)NPAIR*4);
    int*    cnts  = (int*)   take((E_+1)*4);
    int*    offs  = (int*)   take((E_+1)*4);
    int*    etok  = (int*)   take((size_t)NENT*4);
    float*  egate = (float*) take((size_t)NENT*4);
    int*    ppos  = (int*)   take((size_t)NPAIR*4);
    int*    blk_e = (int*)   take((size_t)MAXWORK*4);
    int*    blk_ro= (int*)   take((size_t)MAXWORK*4);
    int*    nwork = (int*)   take(4);
    ushort* xbf   = (ushort*)take((size_t)T_*H_*2);
    ushort* h1buf = (ushort*)take((size_t)NENT*I_*2);
    float*  ybuf  = (float*) take((size_t)NENT*H_*4);

    x_cvt      <<<(T_*H_)/(256*4), 256, 0, stream>>>(x, xbf);
    moe_router <<<T_, 64, 0, stream>>>(x, rw, rb, eb, idxb, gateb);
    moe_build  <<<1, 256, 0, stream>>>(idxb, gateb, cnts, offs, etok, egate, ppos,
                                       blk_e, blk_ro, nwork);
    moe_stage1 <<<dim3(MAXWORK, I_/BN), 256, 0, stream>>>(xbf, w1, b1, w3, b3,
                                                          sw1, sb1, sw3, sb3,
                                                          cnts, offs, etok,
                                                          blk_e, blk_ro, nwork, h1buf);
    moe_stage2 <<<dim3(MAXWORK, H_/BN), 256, 0, stream>>>(h1buf, w2, b2, sw2, sb2,
                                                          cnts, offs, egate,
                                                          blk_e, blk_ro, nwork, ybuf);
    moe_combine<<<T_, 128, 0, stream>>>(ybuf, ppos, out);
}

// Round 10
// 282.030 us; speedup vs baseline: 1.2733x; 1.2733x over previous
//
#include <hip/hip_runtime.h>
#include <math.h>

// Problem constants (fixed by the reference)
#define T_    1024      // B*S tokens
#define H_    512       // hidden
#define I_    1024      // intermediate
#define E_    64        // routed experts
#define K_    4         // top-k
#define NPAIR (T_*K_)   // 4096 routed (token,slot) pairs
#define NENT  (NPAIR + T_)  // + shared-expert entries at [NPAIR + t]

#define BM 128          // rows per work block
#define BN 64           // output cols per block (4 col-groups x 16)
#define MAXWORK 160

typedef float  f32x4  __attribute__((ext_vector_type(4)));
typedef short  bf16x8 __attribute__((ext_vector_type(8)));

__device__ __forceinline__ ushort f2bf(float f) {
    uint u = __float_as_uint(f);
    u += 0x7fffu + ((u >> 16) & 1u);   // round-to-nearest-even
    return (ushort)(u >> 16);
}
// packed f32->bf16 (RNE, same as f2bf) - 1 VALU op per 2 elements
__device__ __forceinline__ bf16x8 cvt8pk(f32x4 a, f32x4 b) {
    union { uint u[4]; bf16x8 v; } r;
    asm("v_cvt_pk_bf16_f32 %0, %1, %2" : "=v"(r.u[0]) : "v"(a[0]), "v"(a[1]));
    asm("v_cvt_pk_bf16_f32 %0, %1, %2" : "=v"(r.u[1]) : "v"(a[2]), "v"(a[3]));
    asm("v_cvt_pk_bf16_f32 %0, %1, %2" : "=v"(r.u[2]) : "v"(b[0]), "v"(b[1]));
    asm("v_cvt_pk_bf16_f32 %0, %1, %2" : "=v"(r.u[3]) : "v"(b[2]), "v"(b[3]));
    return r.v;
}

// ---------------------------------------------------------------------------
// x -> bf16 pre-pass (2 MB, ~2 us)
// ---------------------------------------------------------------------------
__global__ __launch_bounds__(256) void x_cvt(const float* __restrict__ x,
                                             ushort* __restrict__ xb)
{
    const int i = blockIdx.x*256 + threadIdx.x;     // T_*H_/4 float4s
    float4 v = reinterpret_cast<const float4*>(x)[i];
    reinterpret_cast<ushort4*>(xb)[i] =
        make_ushort4(f2bf(v.x), f2bf(v.y), f2bf(v.z), f2bf(v.w));
}

// ---------------------------------------------------------------------------
// Router: one 64-thread block per token.
// ---------------------------------------------------------------------------
__global__ __launch_bounds__(64) void moe_router(
    const float* __restrict__ x, const float* __restrict__ rw,
    const float* __restrict__ rb, const float* __restrict__ eb,
    int* __restrict__ idx_out, float* __restrict__ gate_out)
{
    const int t = blockIdx.x;
    const int lane = threadIdx.x;  // 0..63
    __shared__ float xs[H_];
    __shared__ float lg[E_];
    __shared__ float bs[E_];
    for (int i = lane; i < H_; i += 64) xs[i] = x[(size_t)t*H_ + i];
    bs[lane] = eb[lane];
    __syncthreads();
    float acc = 0.f;
    const float* wrow = rw + (size_t)lane*H_;
    for (int k = 0; k < H_; k += 4) {
        float4 w4 = *reinterpret_cast<const float4*>(wrow + k);
        acc = fmaf(xs[k+0], w4.x, acc);
        acc = fmaf(xs[k+1], w4.y, acc);
        acc = fmaf(xs[k+2], w4.z, acc);
        acc = fmaf(xs[k+3], w4.w, acc);
    }
    lg[lane] = acc + rb[lane];
    __syncthreads();
    if (lane == 0) {
        unsigned long long used = 0ull;
        int sel[K_]; float orig[K_];
        for (int k = 0; k < K_; ++k) {
            float best = -INFINITY; int bi = 0;
            for (int e = 0; e < E_; ++e) {
                if (used & (1ull << e)) continue;
                float v = lg[e] + bs[e];
                if (v > best) { best = v; bi = e; }   // strict > : lowest idx on tie
            }
            used |= (1ull << bi);
            sel[k] = bi; orig[k] = lg[bi];
        }
        float s[K_]; float sum = 0.f;
        for (int k = 0; k < K_; ++k) { s[k] = 1.f/(1.f + __expf(-orig[k])); sum += s[k]; }
        sum = fmaxf(sum, 1e-12f);
        for (int k = 0; k < K_; ++k) {
            idx_out[t*K_ + k] = sel[k];
            gate_out[t*K_ + k] = s[k] / sum;
        }
    }
}

// ---------------------------------------------------------------------------
// Build per-expert token lists + flattened row-block work list (single block).
// ---------------------------------------------------------------------------
__global__ __launch_bounds__(256) void moe_build(
    const int* __restrict__ idx, const float* __restrict__ gates,
    int* __restrict__ cnts, int* __restrict__ offs,
    int* __restrict__ entry_token, float* __restrict__ entry_gate,
    int* __restrict__ pair_pos,
    int* __restrict__ blk_e, int* __restrict__ blk_ro, int* __restrict__ nwork)
{
    __shared__ int c[E_];
    __shared__ int run[E_];
    const int tid = threadIdx.x;
    if (tid < E_) c[tid] = 0;
    __syncthreads();
    for (int p = tid; p < NPAIR; p += 256) atomicAdd(&c[idx[p]], 1);
    __syncthreads();
    if (tid == 0) {
        int o = 0;
        for (int e = 0; e < E_; ++e) { run[e] = o; offs[e] = o; cnts[e] = c[e]; o += c[e]; }
        offs[E_] = NPAIR;   // shared-expert entries
        cnts[E_] = T_;
        int nb = 0;
        for (int e = 0; e <= E_; ++e) {
            int n = (e < E_) ? c[e] : T_;
            for (int ro = 0; ro < n; ro += BM) { blk_e[nb] = e; blk_ro[nb] = ro; ++nb; }
        }
        nwork[0] = nb;
    }
    __syncthreads();
    for (int p = tid; p < NPAIR; p += 256) {
        int e = idx[p];
        int pos = atomicAdd(&run[e], 1);
        entry_token[pos] = p / K_;
        entry_gate[pos]  = gates[p];
        pair_pos[p]      = pos;
    }
    for (int t = tid; t < T_; t += 256) {
        entry_token[NPAIR + t] = t;
        entry_gate[NPAIR + t]  = 1.0f;
    }
}

// ---------------------------------------------------------------------------
// Stage 1: h1 = silu(X w1^T + b1) * (X w3^T + b3) -> bf16
// X panel (128x512 bf16 = 128 KB) loaded to LDS ONCE (XOR-swizzled chunks),
// then a BARRIER-FREE K-loop: each of 8 waves independently streams its own
// 16 weight rows (fp32) direct-to-register with 1-step named prefetch sets,
// cvt_pk -> MFMA. Wave pairs split the 128 rows (wid>>2). No convoy.
// ---------------------------------------------------------------------------
__global__ __launch_bounds__(512, 2) void moe_stage1(
    const ushort* __restrict__ xbf,
    const float* __restrict__ w1, const float* __restrict__ b1,
    const float* __restrict__ w3, const float* __restrict__ b3,
    const float* __restrict__ sw1, const float* __restrict__ sb1,
    const float* __restrict__ sw3, const float* __restrict__ sb3,
    const int* __restrict__ cnts, const int* __restrict__ offs,
    const int* __restrict__ entry_token,
    const int* __restrict__ blk_e, const int* __restrict__ blk_ro,
    const int* __restrict__ nwork,
    ushort* __restrict__ h1buf)
{
    const int w = blockIdx.x;
    if (w >= nwork[0]) return;
    const int e  = blk_e[w];
    const int ro = blk_ro[w];
    const int itile = blockIdx.y;   // 0..15 (I_/BN)
    const int n = cnts[e];
    const int off = offs[e];
    const int rows = min(BM, n - ro);
    const float* W1 = (e < E_) ? (w1 + (size_t)e*I_*H_) : sw1;
    const float* W3 = (e < E_) ? (w3 + (size_t)e*I_*H_) : sw3;
    const float* B1 = (e < E_) ? (b1 + (size_t)e*I_) : sb1;
    const float* B3 = (e < E_) ? (b3 + (size_t)e*I_) : sb3;

    __shared__ __align__(16) ushort Xs[BM*H_];   // 128 KB (R3 proved >64KB OK)

    const int tid  = threadIdx.x;
    const int lane = tid & 63;
    const int wid  = tid >> 6;          // 0..7
    const int colg = wid & 3;           // col group -> 16 cols
    const int rbase = (wid >> 2) * 64;  // row half 0 / 64
    const int l15  = lane & 15;
    const int lg   = lane >> 4;         // 0..3

    // ---- X fill: 128 rows x 64 chunks(16B), chunk c stored at c ^ (r&7) ----
    // Rows beyond 'rows' read a neighboring valid entry (entries are packed);
    // garbage only reaches masked output rows.
    #pragma unroll
    for (int i = 0; i < 16; ++i) {
        const int id = tid + i*512;     // 0..8191
        const int r = id >> 6, c = id & 63;
        const int tok = entry_token[off + ro + r];
        uint4 v = *reinterpret_cast<const uint4*>(xbf + (size_t)tok*H_ + c*8);
        *reinterpret_cast<uint4*>((char*)Xs + r*1024 + (((c ^ (r & 7))) << 4)) = v;
    }
    __syncthreads();                    // the ONLY barrier in this kernel

    // ---- per-wave weight stream ----
    const int ncol = itile*BN + colg*16 + l15;      // output col / weight row
    const float* b1p = W1 + (size_t)ncol*H_ + lg*8;
    const float* b3p = W3 + (size_t)ncol*H_ + lg*8;

    f32x4 acc1[4] = {};
    f32x4 acc3[4] = {};
    f32x4 s0[4], s1[4];   // named prefetch sets: [w1lo, w1hi, w3lo, w3hi]

    #define LW1(S, kc) do {                                      \
        S[0] = *reinterpret_cast<const f32x4*>(b1p + (kc));      \
        S[1] = *reinterpret_cast<const f32x4*>(b1p + (kc) + 4);  \
        S[2] = *reinterpret_cast<const f32x4*>(b3p + (kc));      \
        S[3] = *reinterpret_cast<const f32x4*>(b3p + (kc) + 4);  \
    } while (0)

    #define MFMA8(kc, f1, f3) do {                                             \
        _Pragma("unroll")                                                      \
        for (int m = 0; m < 4; ++m) {                                          \
            const int r_ = rbase + m*16 + l15;                                 \
            bf16x8 a_ = *reinterpret_cast<const bf16x8*>(                      \
                (const char*)Xs + r_*1024 + (((((kc) >> 3) + lg) ^ (r_ & 7)) << 4)); \
            acc1[m] = __builtin_amdgcn_mfma_f32_16x16x32_bf16(a_, f1, acc1[m], 0, 0, 0); \
            acc3[m] = __builtin_amdgcn_mfma_f32_16x16x32_bf16(a_, f3, acc3[m], 0, 0, 0); \
        }                                                                      \
    } while (0)

    LW1(s0, 0);
    for (int tt = 0; tt < 16; tt += 2) {
        {   // even step: consume s0, prefetch s1
            const int kc = tt*32;
            if (tt + 1 < 16) LW1(s1, kc + 32);
            bf16x8 f1 = cvt8pk(s0[0], s0[1]);
            bf16x8 f3 = cvt8pk(s0[2], s0[3]);
            MFMA8(kc, f1, f3);
        }
        {   // odd step: consume s1, prefetch s0
            const int kc = tt*32 + 32;
            if (tt + 2 < 16) LW1(s0, kc + 32);
            bf16x8 f1 = cvt8pk(s1[0], s1[1]);
            bf16x8 f3 = cvt8pk(s1[2], s1[3]);
            MFMA8(kc, f1, f3);
        }
    }
    #undef LW1
    #undef MFMA8

    // epilogue: silu(z1)*z3 -> bf16. C/D: row=(lane>>4)*4+j, col=l15 (=ncol)
    const float bv1 = B1[ncol];
    const float bv3 = B3[ncol];
    #pragma unroll
    for (int m = 0; m < 4; ++m) {
        #pragma unroll
        for (int j = 0; j < 4; ++j) {
            const int rl = rbase + m*16 + lg*4 + j;
            if (rl < rows) {
                float z1 = acc1[m][j] + bv1;
                float z3 = acc3[m][j] + bv3;
                float h = z1 / (1.f + __expf(-z1)) * z3;
                h1buf[(size_t)(off+ro+rl)*I_ + ncol] = f2bf(h);
            }
        }
    }
}

// ---------------------------------------------------------------------------
// Stage 2: y = gate * (h1 @ w2^T + b2) -> fp32. Same template; K=1024 done
// in two 512-wide LDS halves (3 barriers total), barrier-free K-loops.
// ---------------------------------------------------------------------------
__global__ __launch_bounds__(512, 2) void moe_stage2(
    const ushort* __restrict__ h1buf,
    const float* __restrict__ w2, const float* __restrict__ b2,
    const float* __restrict__ sw2, const float* __restrict__ sb2,
    const int* __restrict__ cnts, const int* __restrict__ offs,
    const float* __restrict__ entry_gate,
    const int* __restrict__ blk_e, const int* __restrict__ blk_ro,
    const int* __restrict__ nwork,
    float* __restrict__ ybuf)
{
    const int w = blockIdx.x;
    if (w >= nwork[0]) return;
    const int e  = blk_e[w];
    const int ro = blk_ro[w];
    const int htile = blockIdx.y;   // 0..7 (H_/BN)
    const int n = cnts[e];
    const int off = offs[e];
    const int rows = min(BM, n - ro);
    const float* W2 = (e < E_) ? (w2 + (size_t)e*H_*I_) : sw2;
    const float* B2 = (e < E_) ? (b2 + (size_t)e*H_) : sb2;

    __shared__ __align__(16) ushort Hs[BM*512];   // 128 KB (one K-half)

    const int tid  = threadIdx.x;
    const int lane = tid & 63;
    const int wid  = tid >> 6;
    const int colg = wid & 3;
    const int rbase = (wid >> 2) * 64;
    const int l15  = lane & 15;
    const int lg   = lane >> 4;

    const int ncol = htile*BN + colg*16 + l15;
    const float* bp = W2 + (size_t)ncol*I_ + lg*8;

    f32x4 acc[4] = {};
    f32x4 s0[2], s1[2];

    #define LW2(S, kc) do {                                     \
        S[0] = *reinterpret_cast<const f32x4*>(bp + (kc));      \
        S[1] = *reinterpret_cast<const f32x4*>(bp + (kc) + 4);  \
    } while (0)

    #define MFMA4(kcl, f) do {                                                 \
        _Pragma("unroll")                                                      \
        for (int m = 0; m < 4; ++m) {                                          \
            const int r_ = rbase + m*16 + l15;                                 \
            bf16x8 a_ = *reinterpret_cast<const bf16x8*>(                      \
                (const char*)Hs + r_*1024 + (((((kcl) >> 3) + lg) ^ (r_ & 7)) << 4)); \
            acc[m] = __builtin_amdgcn_mfma_f32_16x16x32_bf16(a_, f, acc[m], 0, 0, 0); \
        }                                                                      \
    } while (0)

    for (int h = 0; h < 2; ++h) {
        if (h) __syncthreads();     // all waves done reading previous half
        #pragma unroll
        for (int i = 0; i < 16; ++i) {
            const int id = tid + i*512;
            const int r = id >> 6, c = id & 63;
            uint4 v = *reinterpret_cast<const uint4*>(
                h1buf + (size_t)(off + ro + r)*I_ + h*512 + c*8);
            *reinterpret_cast<uint4*>((char*)Hs + r*1024 + (((c ^ (r & 7))) << 4)) = v;
        }
        __syncthreads();

        const int kb = h*512;
        LW2(s0, kb);
        for (int tt = 0; tt < 16; tt += 2) {
            {   // even
                const int kc = kb + tt*32;
                if (tt + 1 < 16) LW2(s1, kc + 32);
                bf16x8 f = cvt8pk(s0[0], s0[1]);
                MFMA4(tt*32, f);
            }
            {   // odd
                const int kc = kb + tt*32 + 32;
                if (tt + 2 < 16) LW2(s0, kc + 32);
                bf16x8 f = cvt8pk(s1[0], s1[1]);
                MFMA4(tt*32 + 32, f);
            }
        }
    }
    #undef LW2
    #undef MFMA4

    const float bv = B2[ncol];
    #pragma unroll
    for (int m = 0; m < 4; ++m) {
        #pragma unroll
        for (int j = 0; j < 4; ++j) {
            const int rl = rbase + m*16 + lg*4 + j;
            if (rl < rows) {
                const float g = entry_gate[off + ro + rl];
                ybuf[(size_t)(off+ro+rl)*H_ + ncol] = (acc[m][j] + bv) * g;
            }
        }
    }
}

// ---------------------------------------------------------------------------
// Combine: out[t] = y_shared[t] + sum_k y_routed[pair_pos[t,k]]
// ---------------------------------------------------------------------------
__global__ __launch_bounds__(128) void moe_combine(
    const float* __restrict__ ybuf, const int* __restrict__ pair_pos,
    float* __restrict__ out)
{
    const int t = blockIdx.x;
    const int lane = threadIdx.x;     // 128 threads * 4 floats = 512
    const int h = lane * 4;
    const int p0 = pair_pos[t*K_+0], p1 = pair_pos[t*K_+1];
    const int p2 = pair_pos[t*K_+2], p3 = pair_pos[t*K_+3];
    float4 a  = *reinterpret_cast<const float4*>(ybuf + (size_t)(NPAIR+t)*H_ + h);
    float4 v0 = *reinterpret_cast<const float4*>(ybuf + (size_t)p0*H_ + h);
    float4 v1 = *reinterpret_cast<const float4*>(ybuf + (size_t)p1*H_ + h);
    float4 v2 = *reinterpret_cast<const float4*>(ybuf + (size_t)p2*H_ + h);
    float4 v3 = *reinterpret_cast<const float4*>(ybuf + (size_t)p3*H_ + h);
    float4 r;
    r.x = a.x + v0.x + v1.x + v2.x + v3.x;
    r.y = a.y + v0.y + v1.y + v2.y + v3.y;
    r.z = a.z + v0.z + v1.z + v2.z + v3.z;
    r.w = a.w + v0.w + v1.w + v2.w + v3.w;
    *reinterpret_cast<float4*>(out + (size_t)t*H_ + h) = r;
}

extern "C" void kernel_launch(void* const* d_in, const int* in_sizes, int n_in,
                              void* d_out, int out_size, void* d_ws, size_t ws_size,
                              hipStream_t stream)
{
    const float* x   = (const float*)d_in[0];
    const float* rw  = (const float*)d_in[1];
    const float* rb  = (const float*)d_in[2];
    const float* eb  = (const float*)d_in[3];
    const float* sw1 = (const float*)d_in[4];
    const float* sb1 = (const float*)d_in[5];
    const float* sw2 = (const float*)d_in[6];
    const float* sb2 = (const float*)d_in[7];
    const float* sw3 = (const float*)d_in[8];
    const float* sb3 = (const float*)d_in[9];
    const float* w1  = (const float*)d_in[10];
    const float* b1  = (const float*)d_in[11];
    const float* w2  = (const float*)d_in[12];
    const float* b2  = (const float*)d_in[13];
    const float* w3  = (const float*)d_in[14];
    const float* b3  = (const float*)d_in[15];
    float* out = (float*)d_out;

    char* p = (char*)d_ws;
    auto take = [&](size_t bytes) { char* q = p; p += (bytes + 255) & ~(size_t)255; return q; };
    int*    idxb  = (int*)   take((size_t)NPAIR*4);
    float*  gateb = (float*) take((size_t)NPAIR*4);
    int*    cnts  = (int*)   take((E_+1)*4);
    int*    offs  = (int*)   take((E_+1)*4);
    int*    etok  = (int*)   take((size_t)NENT*4);
    float*  egate = (float*) take((size_t)NENT*4);
    int*    ppos  = (int*)   take((size_t)NPAIR*4);
    int*    blk_e = (int*)   take((size_t)MAXWORK*4);
    int*    blk_ro= (int*)   take((size_t)MAXWORK*4);
    int*    nwork = (int*)   take(4);
    ushort* xbf   = (ushort*)take((size_t)T_*H_*2);
    ushort* h1buf = (ushort*)take((size_t)NENT*I_*2);
    float*  ybuf  = (float*) take((size_t)NENT*H_*4);

    x_cvt      <<<(T_*H_)/(256*4), 256, 0, stream>>>(x, xbf);
    moe_router <<<T_, 64, 0, stream>>>(x, rw, rb, eb, idxb, gateb);
    moe_build  <<<1, 256, 0, stream>>>(idxb, gateb, cnts, offs, etok, egate, ppos,
                                       blk_e, blk_ro, nwork);
    moe_stage1 <<<dim3(MAXWORK, I_/BN), 512, 0, stream>>>(xbf, w1, b1, w3, b3,
                                                          sw1, sb1, sw3, sb3,
                                                          cnts, offs, etok,
                                                          blk_e, blk_ro, nwork, h1buf);
    moe_stage2 <<<dim3(MAXWORK, H_/BN), 512, 0, stream>>>(h1buf, w2, b2, sw2, sb2,
                                                          cnts, offs, egate,
                                                          blk_e, blk_ro, nwork, ybuf);
    moe_combine<<<T_, 128, 0, stream>>>(ybuf, ppos, out);
}

// Round 11
// 247.942 us; speedup vs baseline: 1.4483x; 1.1375x over previous
//
#include <hip/hip_runtime.h>
#include <math.h>

// Problem constants (fixed by the reference)
#define T_    1024      // B*S tokens
#define H_    512       // hidden
#define I_    1024      // intermediate
#define E_    64        // routed experts
#define K_    4         // top-k
#define NPAIR (T_*K_)   // 4096 routed (token,slot) pairs
#define NENT  (NPAIR + T_)  // + shared-expert entries at [NPAIR + t]

#define BM 128          // rows per work block (weights read once per expert)
#define BN 32           // output cols per block (small -> many blocks)
#define BKS 64          // k-step (elements)
#define LDP 72          // padded LDS row (elements): 144B stride, 2-way max
#define MAXWORK 160
#define NT1 (H_/BKS)    // 8
#define NT2 (I_/BKS)    // 16

typedef float  f32x4  __attribute__((ext_vector_type(4)));
typedef short  bf16x8 __attribute__((ext_vector_type(8)));

__device__ __forceinline__ ushort f2bf(float f) {
    uint u = __float_as_uint(f);
    u += 0x7fffu + ((u >> 16) & 1u);   // round-to-nearest-even
    return (ushort)(u >> 16);
}
__device__ __forceinline__ ushort4 cvt4(float4 v) {
    return make_ushort4(f2bf(v.x), f2bf(v.y), f2bf(v.z), f2bf(v.w));
}

// ---------------------------------------------------------------------------
// x -> bf16 pre-pass (2 MB, ~2 us)
// ---------------------------------------------------------------------------
__global__ __launch_bounds__(256) void x_cvt(const float* __restrict__ x,
                                             ushort* __restrict__ xb)
{
    const int i = blockIdx.x*256 + threadIdx.x;     // T_*H_/4 float4s
    float4 v = reinterpret_cast<const float4*>(x)[i];
    reinterpret_cast<ushort4*>(xb)[i] =
        make_ushort4(f2bf(v.x), f2bf(v.y), f2bf(v.z), f2bf(v.w));
}

// ---------------------------------------------------------------------------
// Router: one 64-thread block per token.
// ---------------------------------------------------------------------------
__global__ __launch_bounds__(64) void moe_router(
    const float* __restrict__ x, const float* __restrict__ rw,
    const float* __restrict__ rb, const float* __restrict__ eb,
    int* __restrict__ idx_out, float* __restrict__ gate_out)
{
    const int t = blockIdx.x;
    const int lane = threadIdx.x;  // 0..63
    __shared__ float xs[H_];
    __shared__ float lg[E_];
    __shared__ float bs[E_];
    for (int i = lane; i < H_; i += 64) xs[i] = x[(size_t)t*H_ + i];
    bs[lane] = eb[lane];
    __syncthreads();
    float acc = 0.f;
    const float* wrow = rw + (size_t)lane*H_;
    for (int k = 0; k < H_; k += 4) {
        float4 w4 = *reinterpret_cast<const float4*>(wrow + k);
        acc = fmaf(xs[k+0], w4.x, acc);
        acc = fmaf(xs[k+1], w4.y, acc);
        acc = fmaf(xs[k+2], w4.z, acc);
        acc = fmaf(xs[k+3], w4.w, acc);
    }
    lg[lane] = acc + rb[lane];
    __syncthreads();
    if (lane == 0) {
        unsigned long long used = 0ull;
        int sel[K_]; float orig[K_];
        for (int k = 0; k < K_; ++k) {
            float best = -INFINITY; int bi = 0;
            for (int e = 0; e < E_; ++e) {
                if (used & (1ull << e)) continue;
                float v = lg[e] + bs[e];
                if (v > best) { best = v; bi = e; }   // strict > : lowest idx on tie
            }
            used |= (1ull << bi);
            sel[k] = bi; orig[k] = lg[bi];
        }
        float s[K_]; float sum = 0.f;
        for (int k = 0; k < K_; ++k) { s[k] = 1.f/(1.f + __expf(-orig[k])); sum += s[k]; }
        sum = fmaxf(sum, 1e-12f);
        for (int k = 0; k < K_; ++k) {
            idx_out[t*K_ + k] = sel[k];
            gate_out[t*K_ + k] = s[k] / sum;
        }
    }
}

// ---------------------------------------------------------------------------
// Build per-expert token lists + flattened row-block work list (single block).
// ---------------------------------------------------------------------------
__global__ __launch_bounds__(256) void moe_build(
    const int* __restrict__ idx, const float* __restrict__ gates,
    int* __restrict__ cnts, int* __restrict__ offs,
    int* __restrict__ entry_token, float* __restrict__ entry_gate,
    int* __restrict__ pair_pos,
    int* __restrict__ blk_e, int* __restrict__ blk_ro, int* __restrict__ nwork)
{
    __shared__ int c[E_];
    __shared__ int run[E_];
    const int tid = threadIdx.x;
    if (tid < E_) c[tid] = 0;
    __syncthreads();
    for (int p = tid; p < NPAIR; p += 256) atomicAdd(&c[idx[p]], 1);
    __syncthreads();
    if (tid == 0) {
        int o = 0;
        for (int e = 0; e < E_; ++e) { run[e] = o; offs[e] = o; cnts[e] = c[e]; o += c[e]; }
        offs[E_] = NPAIR;   // shared-expert entries
        cnts[E_] = T_;
        int nb = 0;
        for (int e = 0; e <= E_; ++e) {
            int n = (e < E_) ? c[e] : T_;
            for (int ro = 0; ro < n; ro += BM) { blk_e[nb] = e; blk_ro[nb] = ro; ++nb; }
        }
        nwork[0] = nb;
    }
    __syncthreads();
    for (int p = tid; p < NPAIR; p += 256) {
        int e = idx[p];
        int pos = atomicAdd(&run[e], 1);
        entry_token[pos] = p / K_;
        entry_gate[pos]  = gates[p];
        pair_pos[p]      = pos;
    }
    for (int t = tid; t < T_; t += 256) {
        entry_token[NPAIR + t] = t;
        entry_gate[NPAIR + t]  = 1.0f;
    }
}

// ---------------------------------------------------------------------------
// Stage 1: h1 = silu(X w1^T + b1) * (X w3^T + b3) -> bf16
// R1-recipe staging (reg->cvt->LDS, plain syncthreads, issue-next-early) at
// BN=32: 2304 real blocks (2x R1), per-block weight bytes halved, (512,6)
// bounds -> ~3 blocks/CU resident. Cross-block overlap hides HBM latency.
// 4 pipelined loads/thread. LDS 27.6 KB.
// ---------------------------------------------------------------------------
__global__ __launch_bounds__(512, 6) void moe_stage1(
    const ushort* __restrict__ xbf,
    const float* __restrict__ w1, const float* __restrict__ b1,
    const float* __restrict__ w3, const float* __restrict__ b3,
    const float* __restrict__ sw1, const float* __restrict__ sb1,
    const float* __restrict__ sw3, const float* __restrict__ sb3,
    const int* __restrict__ cnts, const int* __restrict__ offs,
    const int* __restrict__ entry_token,
    const int* __restrict__ blk_e, const int* __restrict__ blk_ro,
    const int* __restrict__ nwork,
    ushort* __restrict__ h1buf)
{
    const int w = blockIdx.y;
    if (w >= nwork[0]) return;
    const int e  = blk_e[w];
    const int ro = blk_ro[w];
    const int itile = blockIdx.x;   // 0..31 (I_/BN)
    const int n = cnts[e];
    const int off = offs[e];
    const int rows = min(BM, n - ro);
    const float* W1 = (e < E_) ? (w1 + (size_t)e*I_*H_) : sw1;
    const float* W3 = (e < E_) ? (w3 + (size_t)e*I_*H_) : sw3;
    const float* B1 = (e < E_) ? (b1 + (size_t)e*I_) : sb1;
    const float* B3 = (e < E_) ? (b3 + (size_t)e*I_) : sb3;

    __shared__ ushort Xs [BM][LDP];   // 18432 B
    __shared__ ushort W1s[BN][LDP];   //  4608 B
    __shared__ ushort W3s[BN][LDP];   //  4608 B -> 27.6 KB

    const int tid  = threadIdx.x;
    const int lane = tid & 63;
    const int wid  = tid >> 6;          // 0..7
    const int wm   = wid >> 1;          // 0..3 -> 32 rows each
    const int wn   = wid & 1;           // 0..1 -> 16 cols each
    const int l15  = lane & 15;
    const int lg   = lane >> 4;         // 0..3

    // staging thread map
    const int xr = tid >> 3;            // 0..63 (+64 on 2nd chunk)
    const int xc = tid & 7;             // 16B chunk of bf16 row (8 per 64-el row)
    const int wr = tid >> 4;            // 0..31
    const int wc = tid & 15;            // float4 seg

    // K-invariant row pointers. Rows beyond 'rows' read a neighboring valid
    // entry (entries are packed over [0,NENT)); garbage only reaches masked
    // output rows.
    const ushort* xp[2];
    #pragma unroll
    for (int i = 0; i < 2; ++i)
        xp[i] = xbf + (size_t)entry_token[off + ro + xr + i*64]*H_ + xc*8;
    const float* w1p = W1 + (size_t)(itile*BN + wr)*H_ + wc*4;
    const float* w3p = W3 + (size_t)(itile*BN + wr)*H_ + wc*4;

    f32x4 acc1[2] = {};
    f32x4 acc3[2] = {};

    // pipeline registers (single named set, R1-style)
    uint4  hx[2];
    float4 v1, v3;

    auto issue = [&](int kc) {
        #pragma unroll
        for (int i = 0; i < 2; ++i)
            hx[i] = *reinterpret_cast<const uint4*>(xp[i] + kc);
        v1 = *reinterpret_cast<const float4*>(w1p + kc);
        v3 = *reinterpret_cast<const float4*>(w3p + kc);
    };
    auto stwrite = [&]() {
        #pragma unroll
        for (int i = 0; i < 2; ++i)
            *reinterpret_cast<uint4*>(&Xs[xr + i*64][xc*8]) = hx[i];
        *reinterpret_cast<ushort4*>(&W1s[wr][wc*4]) = cvt4(v1);
        *reinterpret_cast<ushort4*>(&W3s[wr][wc*4]) = cvt4(v3);
    };

    issue(0);
    for (int t = 0; t < NT1; ++t) {
        __syncthreads();               // prev MFMA done reading LDS
        stwrite();                     // step t data (issued a full step ago)
        if (t + 1 < NT1) issue((t + 1)*BKS);   // fly during MFMA(t)
        __syncthreads();
        #pragma unroll
        for (int s = 0; s < 2; ++s) {
            bf16x8 a[2], bb1, bb3;
            #pragma unroll
            for (int f = 0; f < 2; ++f)
                a[f] = *reinterpret_cast<const bf16x8*>(&Xs[wm*32 + f*16 + l15][s*32 + lg*8]);
            bb1 = *reinterpret_cast<const bf16x8*>(&W1s[wn*16 + l15][s*32 + lg*8]);
            bb3 = *reinterpret_cast<const bf16x8*>(&W3s[wn*16 + l15][s*32 + lg*8]);
            #pragma unroll
            for (int f = 0; f < 2; ++f) {
                acc1[f] = __builtin_amdgcn_mfma_f32_16x16x32_bf16(a[f], bb1, acc1[f], 0, 0, 0);
                acc3[f] = __builtin_amdgcn_mfma_f32_16x16x32_bf16(a[f], bb3, acc3[f], 0, 0, 0);
            }
        }
    }

    // epilogue: silu(z1)*z3 -> bf16. C/D: row=(lane>>4)*4+j, col=l15
    const int col = itile*BN + wn*16 + l15;
    const float bv1 = B1[col];
    const float bv3 = B3[col];
    #pragma unroll
    for (int f = 0; f < 2; ++f) {
        #pragma unroll
        for (int j = 0; j < 4; ++j) {
            const int rl = wm*32 + f*16 + lg*4 + j;
            if (rl < rows) {
                float z1 = acc1[f][j] + bv1;
                float z3 = acc3[f][j] + bv3;
                float h = z1 / (1.f + __expf(-z1)) * z3;
                h1buf[(size_t)(off+ro+rl)*I_ + col] = f2bf(h);
            }
        }
    }
}

// ---------------------------------------------------------------------------
// Stage 2: y = gate * (h1 @ w2^T + b2) -> fp32. Same template, BN=32.
// LDS 23 KB. 3 loads/thread.
// ---------------------------------------------------------------------------
__global__ __launch_bounds__(512, 6) void moe_stage2(
    const ushort* __restrict__ h1buf,
    const float* __restrict__ w2, const float* __restrict__ b2,
    const float* __restrict__ sw2, const float* __restrict__ sb2,
    const int* __restrict__ cnts, const int* __restrict__ offs,
    const float* __restrict__ entry_gate,
    const int* __restrict__ blk_e, const int* __restrict__ blk_ro,
    const int* __restrict__ nwork,
    float* __restrict__ ybuf)
{
    const int w = blockIdx.y;
    if (w >= nwork[0]) return;
    const int e  = blk_e[w];
    const int ro = blk_ro[w];
    const int htile = blockIdx.x;   // 0..15 (H_/BN)
    const int n = cnts[e];
    const int off = offs[e];
    const int rows = min(BM, n - ro);
    const float* W2 = (e < E_) ? (w2 + (size_t)e*H_*I_) : sw2;
    const float* B2 = (e < E_) ? (b2 + (size_t)e*H_) : sb2;

    __shared__ ushort Hs[BM][LDP];    // 18432 B
    __shared__ ushort Ws[BN][LDP];    //  4608 B -> 23 KB

    const int tid  = threadIdx.x;
    const int lane = tid & 63;
    const int wid  = tid >> 6;          // 0..7
    const int wm   = wid >> 1;
    const int wn   = wid & 1;
    const int l15  = lane & 15;
    const int lg   = lane >> 4;

    const int hr = tid >> 3;            // 0..63 (+64)
    const int hc = tid & 7;
    const int wr = tid >> 4;            // 0..31
    const int wc = tid & 15;

    const ushort* hp[2];
    #pragma unroll
    for (int i = 0; i < 2; ++i)
        hp[i] = h1buf + (size_t)(off + ro + hr + i*64)*I_ + hc*8;
    const float* wp = W2 + (size_t)(htile*BN + wr)*I_ + wc*4;

    f32x4 acc[2] = {};

    uint4  hv[2];
    float4 wv;

    auto issue = [&](int kc) {
        #pragma unroll
        for (int i = 0; i < 2; ++i)
            hv[i] = *reinterpret_cast<const uint4*>(hp[i] + kc);
        wv = *reinterpret_cast<const float4*>(wp + kc);
    };
    auto stwrite = [&]() {
        #pragma unroll
        for (int i = 0; i < 2; ++i)
            *reinterpret_cast<uint4*>(&Hs[hr + i*64][hc*8]) = hv[i];
        *reinterpret_cast<ushort4*>(&Ws[wr][wc*4]) = cvt4(wv);
    };

    issue(0);
    for (int t = 0; t < NT2; ++t) {
        __syncthreads();
        stwrite();
        if (t + 1 < NT2) issue((t + 1)*BKS);
        __syncthreads();
        #pragma unroll
        for (int s = 0; s < 2; ++s) {
            bf16x8 a[2], bb;
            #pragma unroll
            for (int f = 0; f < 2; ++f)
                a[f] = *reinterpret_cast<const bf16x8*>(&Hs[wm*32 + f*16 + l15][s*32 + lg*8]);
            bb = *reinterpret_cast<const bf16x8*>(&Ws[wn*16 + l15][s*32 + lg*8]);
            #pragma unroll
            for (int f = 0; f < 2; ++f)
                acc[f] = __builtin_amdgcn_mfma_f32_16x16x32_bf16(a[f], bb, acc[f], 0, 0, 0);
        }
    }

    const int col = htile*BN + wn*16 + l15;
    const float bv = B2[col];
    #pragma unroll
    for (int f = 0; f < 2; ++f) {
        #pragma unroll
        for (int j = 0; j < 4; ++j) {
            const int rl = wm*32 + f*16 + lg*4 + j;
            if (rl < rows) {
                const float g = entry_gate[off + ro + rl];
                ybuf[(size_t)(off+ro+rl)*H_ + col] = (acc[f][j] + bv) * g;
            }
        }
    }
}

// ---------------------------------------------------------------------------
// Combine: out[t] = y_shared[t] + sum_k y_routed[pair_pos[t,k]]
// ---------------------------------------------------------------------------
__global__ __launch_bounds__(128) void moe_combine(
    const float* __restrict__ ybuf, const int* __restrict__ pair_pos,
    float* __restrict__ out)
{
    const int t = blockIdx.x;
    const int lane = threadIdx.x;     // 128 threads * 4 floats = 512
    const int h = lane * 4;
    const int p0 = pair_pos[t*K_+0], p1 = pair_pos[t*K_+1];
    const int p2 = pair_pos[t*K_+2], p3 = pair_pos[t*K_+3];
    float4 a  = *reinterpret_cast<const float4*>(ybuf + (size_t)(NPAIR+t)*H_ + h);
    float4 v0 = *reinterpret_cast<const float4*>(ybuf + (size_t)p0*H_ + h);
    float4 v1 = *reinterpret_cast<const float4*>(ybuf + (size_t)p1*H_ + h);
    float4 v2 = *reinterpret_cast<const float4*>(ybuf + (size_t)p2*H_ + h);
    float4 v3 = *reinterpret_cast<const float4*>(ybuf + (size_t)p3*H_ + h);
    float4 r;
    r.x = a.x + v0.x + v1.x + v2.x + v3.x;
    r.y = a.y + v0.y + v1.y + v2.y + v3.y;
    r.z = a.z + v0.z + v1.z + v2.z + v3.z;
    r.w = a.w + v0.w + v1.w + v2.w + v3.w;
    *reinterpret_cast<float4*>(out + (size_t)t*H_ + h) = r;
}

extern "C" void kernel_launch(void* const* d_in, const int* in_sizes, int n_in,
                              void* d_out, int out_size, void* d_ws, size_t ws_size,
                              hipStream_t stream)
{
    const float* x   = (const float*)d_in[0];
    const float* rw  = (const float*)d_in[1];
    const float* rb  = (const float*)d_in[2];
    const float* eb  = (const float*)d_in[3];
    const float* sw1 = (const float*)d_in[4];
    const float* sb1 = (const float*)d_in[5];
    const float* sw2 = (const float*)d_in[6];
    const float* sb2 = (const float*)d_in[7];
    const float* sw3 = (const float*)d_in[8];
    const float* sb3 = (const float*)d_in[9];
    const float* w1  = (const float*)d_in[10];
    const float* b1  = (const float*)d_in[11];
    const float* w2  = (const float*)d_in[12];
    const float* b2  = (const float*)d_in[13];
    const float* w3  = (const float*)d_in[14];
    const float* b3  = (const float*)d_in[15];
    float* out = (float*)d_out;

    char* p = (char*)d_ws;
    auto take = [&](size_t bytes) { char* q = p; p += (bytes + 255) & ~(size_t)255; return q; };
    int*    idxb  = (int*)   take((size_t)NPAIR*4);
    float*  gateb = (float*) take((size_t)NPAIR*4);
    int*    cnts  = (int*)   take((E_+1)*4);
    int*    offs  = (int*)   take((E_+1)*4);
    int*    etok  = (int*)   take((size_t)NENT*4);
    float*  egate = (float*) take((size_t)NENT*4);
    int*    ppos  = (int*)   take((size_t)NPAIR*4);
    int*    blk_e = (int*)   take((size_t)MAXWORK*4);
    int*    blk_ro= (int*)   take((size_t)MAXWORK*4);
    int*    nwork = (int*)   take(4);
    ushort* xbf   = (ushort*)take((size_t)T_*H_*2);
    ushort* h1buf = (ushort*)take((size_t)NENT*I_*2);
    float*  ybuf  = (float*) take((size_t)NENT*H_*4);

    x_cvt      <<<(T_*H_)/(256*4), 256, 0, stream>>>(x, xbf);
    moe_router <<<T_, 64, 0, stream>>>(x, rw, rb, eb, idxb, gateb);
    moe_build  <<<1, 256, 0, stream>>>(idxb, gateb, cnts, offs, etok, egate, ppos,
                                       blk_e, blk_ro, nwork);
    moe_stage1 <<<dim3(I_/BN, MAXWORK), 512, 0, stream>>>(xbf, w1, b1, w3, b3,
                                                          sw1, sb1, sw3, sb3,
                                                          cnts, offs, etok,
                                                          blk_e, blk_ro, nwork, h1buf);
    moe_stage2 <<<dim3(H_/BN, MAXWORK), 512, 0, stream>>>(h1buf, w2, b2, sw2, sb2,
                                                          cnts, offs, egate,
                                                          blk_e, blk_ro, nwork, ybuf);
    moe_combine<<<T_, 128, 0, stream>>>(ybuf, ppos, out);
}

// Round 12
// 202.503 us; speedup vs baseline: 1.7733x; 1.2244x over previous
//
#include <hip/hip_runtime.h>
#include <math.h>

// Problem constants (fixed by the reference)
#define T_    1024      // B*S tokens
#define H_    512       // hidden
#define I_    1024      // intermediate
#define E_    64        // routed experts
#define K_    4         // top-k
#define NPAIR (T_*K_)   // 4096 routed (token,slot) pairs
#define NENT  (NPAIR + T_)  // + shared-expert entries at [NPAIR + t]

#define BM 128          // rows per work block
#define BN 64           // output cols per block (I- or H-tile)
#define BKS 64          // k-step (elements)
#define MAXWORK 160
#define NT1 (H_/BKS)    // 8
#define NT2 (I_/BKS)    // 16

typedef float  f32x4  __attribute__((ext_vector_type(4)));
typedef short  bf16x8 __attribute__((ext_vector_type(8)));

__device__ __forceinline__ ushort f2bf(float f) {
    uint u = __float_as_uint(f);
    u += 0x7fffu + ((u >> 16) & 1u);   // round-to-nearest-even
    return (ushort)(u >> 16);
}
__device__ __forceinline__ bf16x8 cvt8(f32x4 a, f32x4 b) {
    bf16x8 r;
    r[0] = (short)f2bf(a[0]); r[1] = (short)f2bf(a[1]);
    r[2] = (short)f2bf(a[2]); r[3] = (short)f2bf(a[3]);
    r[4] = (short)f2bf(b[0]); r[5] = (short)f2bf(b[1]);
    r[6] = (short)f2bf(b[2]); r[7] = (short)f2bf(b[3]);
    return r;
}

// async global->LDS, 16B per lane; LDS dest = wave-uniform base + lane*16
__device__ __forceinline__ void gload16(const void* g, void* lds) {
    __builtin_amdgcn_global_load_lds(
        (const __attribute__((address_space(1))) unsigned int*)g,
        (__attribute__((address_space(3))) unsigned int*)lds, 16, 0, 0);
}

// ---------------------------------------------------------------------------
// Router: one 64-thread block per token.
// ---------------------------------------------------------------------------
__global__ __launch_bounds__(64) void moe_router(
    const float* __restrict__ x, const float* __restrict__ rw,
    const float* __restrict__ rb, const float* __restrict__ eb,
    int* __restrict__ idx_out, float* __restrict__ gate_out)
{
    const int t = blockIdx.x;
    const int lane = threadIdx.x;  // 0..63
    __shared__ float xs[H_];
    __shared__ float lg[E_];
    __shared__ float bs[E_];
    for (int i = lane; i < H_; i += 64) xs[i] = x[(size_t)t*H_ + i];
    bs[lane] = eb[lane];
    __syncthreads();
    float acc = 0.f;
    const float* wrow = rw + (size_t)lane*H_;
    for (int k = 0; k < H_; k += 4) {
        float4 w4 = *reinterpret_cast<const float4*>(wrow + k);
        acc = fmaf(xs[k+0], w4.x, acc);
        acc = fmaf(xs[k+1], w4.y, acc);
        acc = fmaf(xs[k+2], w4.z, acc);
        acc = fmaf(xs[k+3], w4.w, acc);
    }
    lg[lane] = acc + rb[lane];
    __syncthreads();
    if (lane == 0) {
        unsigned long long used = 0ull;
        int sel[K_]; float orig[K_];
        for (int k = 0; k < K_; ++k) {
            float best = -INFINITY; int bi = 0;
            for (int e = 0; e < E_; ++e) {
                if (used & (1ull << e)) continue;
                float v = lg[e] + bs[e];
                if (v > best) { best = v; bi = e; }   // strict > : lowest idx on tie
            }
            used |= (1ull << bi);
            sel[k] = bi; orig[k] = lg[bi];
        }
        float s[K_]; float sum = 0.f;
        for (int k = 0; k < K_; ++k) { s[k] = 1.f/(1.f + __expf(-orig[k])); sum += s[k]; }
        sum = fmaxf(sum, 1e-12f);
        for (int k = 0; k < K_; ++k) {
            idx_out[t*K_ + k] = sel[k];
            gate_out[t*K_ + k] = s[k] / sum;
        }
    }
}

// ---------------------------------------------------------------------------
// Build per-expert token lists + flattened row-block work list (single block).
// ---------------------------------------------------------------------------
__global__ __launch_bounds__(256) void moe_build(
    const int* __restrict__ idx, const float* __restrict__ gates,
    int* __restrict__ cnts, int* __restrict__ offs,
    int* __restrict__ entry_token, float* __restrict__ entry_gate,
    int* __restrict__ pair_pos,
    int* __restrict__ blk_e, int* __restrict__ blk_ro, int* __restrict__ nwork)
{
    __shared__ int c[E_];
    __shared__ int run[E_];
    const int tid = threadIdx.x;
    if (tid < E_) c[tid] = 0;
    __syncthreads();
    for (int p = tid; p < NPAIR; p += 256) atomicAdd(&c[idx[p]], 1);
    __syncthreads();
    if (tid == 0) {
        int o = 0;
        for (int e = 0; e < E_; ++e) { run[e] = o; offs[e] = o; cnts[e] = c[e]; o += c[e]; }
        offs[E_] = NPAIR;   // shared-expert entries
        cnts[E_] = T_;
        int nb = 0;
        for (int e = 0; e <= E_; ++e) {
            int n = (e < E_) ? c[e] : T_;
            for (int ro = 0; ro < n; ro += BM) { blk_e[nb] = e; blk_ro[nb] = ro; ++nb; }
        }
        nwork[0] = nb;
    }
    __syncthreads();
    for (int p = tid; p < NPAIR; p += 256) {
        int e = idx[p];
        int pos = atomicAdd(&run[e], 1);
        entry_token[pos] = p / K_;
        entry_gate[pos]  = gates[p];
        pair_pos[p]      = pos;
    }
    for (int t = tid; t < T_; t += 256) {
        entry_token[NPAIR + t] = t;
        entry_gate[NPAIR + t]  = 1.0f;
    }
}

// ---------------------------------------------------------------------------
// X-pack: xg[entry][512] bf16 = x[entry_token[entry]] (gather ONCE, sorted
// by expert). Stage1's A-panel then streams contiguously like stage2's h1.
// ---------------------------------------------------------------------------
__global__ __launch_bounds__(128) void moe_xpack(
    const float* __restrict__ x, const int* __restrict__ entry_token,
    ushort* __restrict__ xg)
{
    const int row = blockIdx.x;               // 0..NENT-1
    const int tok = entry_token[row];
    const int c = threadIdx.x * 4;            // 128 thr x 4 floats = 512
    float4 v = *reinterpret_cast<const float4*>(x + (size_t)tok*H_ + c);
    *reinterpret_cast<ushort4*>(xg + (size_t)row*H_ + c) =
        make_ushort4(f2bf(v.x), f2bf(v.y), f2bf(v.z), f2bf(v.w));
}

// ---------------------------------------------------------------------------
// Stage 1: h1 = silu(X w1^T + b1) * (X w3^T + b3) -> bf16
// m97 structure (R6, best-known): 256 thr (4 waves, 2x2 of 64x32), single-
// buffered LDS via global_load_lds, 2 barriers/K-step, 48 KB LDS.
// A-panel from xg: CONTIGUOUS entry-ordered rows (no gather in hot loop).
// ---------------------------------------------------------------------------
__global__ __launch_bounds__(256, 3) void moe_stage1(
    const ushort* __restrict__ xg,
    const float* __restrict__ w1, const float* __restrict__ b1,
    const float* __restrict__ w3, const float* __restrict__ b3,
    const float* __restrict__ sw1, const float* __restrict__ sb1,
    const float* __restrict__ sw3, const float* __restrict__ sb3,
    const int* __restrict__ cnts, const int* __restrict__ offs,
    const int* __restrict__ blk_e, const int* __restrict__ blk_ro,
    const int* __restrict__ nwork,
    ushort* __restrict__ h1buf)
{
    const int w = blockIdx.x;
    if (w >= nwork[0]) return;
    const int e  = blk_e[w];
    const int ro = blk_ro[w];
    const int itile = blockIdx.y;   // 0..I_/BN-1
    const int n = cnts[e];
    const int off = offs[e];
    const int rows = min(BM, n - ro);
    const float* W1 = (e < E_) ? (w1 + (size_t)e*I_*H_) : sw1;
    const float* W3 = (e < E_) ? (w3 + (size_t)e*I_*H_) : sw3;
    const float* B1 = (e < E_) ? (b1 + (size_t)e*I_) : sb1;
    const float* B3 = (e < E_) ? (b3 + (size_t)e*I_) : sb3;

    __shared__ __align__(16) ushort XL [BM*BKS];   // 16 KB
    __shared__ __align__(16) float  W1L[BN*BKS];   // 16 KB
    __shared__ __align__(16) float  W3L[BN*BKS];   // 16 KB

    const int tid  = threadIdx.x;
    const int lane = tid & 63;
    const int wid  = tid >> 6;          // 0..3
    const int wm   = wid >> 1;          // 0..1 -> 64 rows
    const int wn   = wid & 1;           // 0..1 -> 32 cols
    const int l15  = lane & 15;
    const int lg   = lane >> 4;         // 0..3

    // --- staging sources (K-invariant, pre-swizzled) ---
    // X: 16 issues of 1KB = 8 rows x 128B. lane -> row j*8+(lane>>3),
    // 16B chunk (lane&7); source col chunk = (lane&7) ^ (row&7).
    // Rows beyond 'rows' read a neighboring valid entry (entries are packed
    // over [0,NENT)); garbage only lands in masked output rows.
    const ushort* xsrc[4];
    // W: 16 issues of 1KB = 4 rows x 256B. lane -> row j*4+(lane>>4),
    // 16B chunk c16=lane&15; 32B chunk c32=c16>>1 swizzled by row&7.
    const float* w1src[4];
    const float* w3src[4];
    #pragma unroll
    for (int i = 0; i < 4; ++i) {
        const int j = wid*4 + i;
        const int rX = j*8 + (lane >> 3);
        const int cX = (lane & 7) ^ (rX & 7);
        xsrc[i] = xg + (size_t)(off + ro + rX)*H_ + cX*8;
        const int rW = j*4 + (lane >> 4);
        const int c32 = ((lane & 15) >> 1) ^ (rW & 7);
        const int colW = c32*8 + (lane & 1)*4;
        w1src[i] = W1 + (size_t)(itile*BN + rW)*H_ + colW;
        w3src[i] = W3 + (size_t)(itile*BN + rW)*H_ + colW;
    }

    f32x4 acc1[4][2] = {};
    f32x4 acc3[4][2] = {};

    for (int t = 0; t < NT1; ++t) {
        const int kc = t * BKS;
        #pragma unroll
        for (int i = 0; i < 4; ++i)
            gload16(xsrc[i] + kc, (char*)XL + (wid*4 + i)*1024);
        #pragma unroll
        for (int i = 0; i < 4; ++i)
            gload16(w1src[i] + kc, (char*)W1L + (wid*4 + i)*1024);
        #pragma unroll
        for (int i = 0; i < 4; ++i)
            gload16(w3src[i] + kc, (char*)W3L + (wid*4 + i)*1024);
        __syncthreads();    // drain: tile ready
        #pragma unroll
        for (int s = 0; s < 2; ++s) {
            bf16x8 a[4];
            #pragma unroll
            for (int fm = 0; fm < 4; ++fm) {
                const int rr = wm*64 + fm*16 + l15;
                a[fm] = *reinterpret_cast<const bf16x8*>(
                    (const char*)XL + rr*128 + (((s*4 + lg) ^ (rr & 7)) << 4));
            }
            bf16x8 b1f[2], b3f[2];
            #pragma unroll
            for (int fn = 0; fn < 2; ++fn) {
                const int rw = wn*32 + fn*16 + l15;
                const int cw = ((s*4 + lg) ^ (rw & 7)) << 5;
                const char* p1 = (const char*)W1L + rw*256 + cw;
                b1f[fn] = cvt8(*reinterpret_cast<const f32x4*>(p1),
                               *reinterpret_cast<const f32x4*>(p1 + 16));
                const char* p3 = (const char*)W3L + rw*256 + cw;
                b3f[fn] = cvt8(*reinterpret_cast<const f32x4*>(p3),
                               *reinterpret_cast<const f32x4*>(p3 + 16));
            }
            #pragma unroll
            for (int fm = 0; fm < 4; ++fm) {
                #pragma unroll
                for (int fn = 0; fn < 2; ++fn) {
                    acc1[fm][fn] = __builtin_amdgcn_mfma_f32_16x16x32_bf16(a[fm], b1f[fn], acc1[fm][fn], 0, 0, 0);
                    acc3[fm][fn] = __builtin_amdgcn_mfma_f32_16x16x32_bf16(a[fm], b3f[fn], acc3[fm][fn], 0, 0, 0);
                }
            }
        }
        __syncthreads();    // readers done before next stage overwrites
    }

    // epilogue: silu(z1)*z3 -> bf16
    #pragma unroll
    for (int fm = 0; fm < 4; ++fm) {
        #pragma unroll
        for (int fn = 0; fn < 2; ++fn) {
            const int col = itile*BN + wn*32 + fn*16 + l15;
            const float bv1 = B1[col];
            const float bv3 = B3[col];
            #pragma unroll
            for (int j = 0; j < 4; ++j) {
                const int rl = wm*64 + fm*16 + lg*4 + j;   // C/D: row=(lane>>4)*4+reg, col=lane&15
                if (rl < rows) {
                    float z1 = acc1[fm][fn][j] + bv1;
                    float z3 = acc3[fm][fn][j] + bv3;
                    float h = z1 / (1.f + __expf(-z1)) * z3;
                    h1buf[(size_t)(off+ro+rl)*I_ + col] = f2bf(h);
                }
            }
        }
    }
}

// ---------------------------------------------------------------------------
// Stage 2: y = gate * (h1 @ w2^T + b2) -> fp32. Same m97 structure (R6).
// H bf16 [128][64] + W2 fp32 [64][64] = 32 KB -> 4 blocks/CU.
// ---------------------------------------------------------------------------
__global__ __launch_bounds__(256, 4) void moe_stage2(
    const ushort* __restrict__ h1buf,
    const float* __restrict__ w2, const float* __restrict__ b2,
    const float* __restrict__ sw2, const float* __restrict__ sb2,
    const int* __restrict__ cnts, const int* __restrict__ offs,
    const float* __restrict__ entry_gate,
    const int* __restrict__ blk_e, const int* __restrict__ blk_ro,
    const int* __restrict__ nwork,
    float* __restrict__ ybuf)
{
    const int w = blockIdx.x;
    if (w >= nwork[0]) return;
    const int e  = blk_e[w];
    const int ro = blk_ro[w];
    const int htile = blockIdx.y;   // 0..H_/BN-1
    const int n = cnts[e];
    const int off = offs[e];
    const int rows = min(BM, n - ro);
    const float* W2 = (e < E_) ? (w2 + (size_t)e*H_*I_) : sw2;
    const float* B2 = (e < E_) ? (b2 + (size_t)e*H_) : sb2;

    __shared__ __align__(16) ushort HL [BM*BKS];   // 16 KB
    __shared__ __align__(16) float  W2L[BN*BKS];   // 16 KB

    const int tid  = threadIdx.x;
    const int lane = tid & 63;
    const int wid  = tid >> 6;          // 0..3
    const int wm   = wid >> 1;
    const int wn   = wid & 1;
    const int l15  = lane & 15;
    const int lg   = lane >> 4;

    const ushort* hsrc[4];
    const float*  wsrc[4];
    #pragma unroll
    for (int i = 0; i < 4; ++i) {
        const int j = wid*4 + i;
        const int rH = j*8 + (lane >> 3);
        const int cH = (lane & 7) ^ (rH & 7);
        hsrc[i] = h1buf + (size_t)(off + ro + rH)*I_ + cH*8;
        const int rW = j*4 + (lane >> 4);
        const int c32 = ((lane & 15) >> 1) ^ (rW & 7);
        wsrc[i] = W2 + (size_t)(htile*BN + rW)*I_ + c32*8 + (lane & 1)*4;
    }

    f32x4 acc[4][2] = {};

    for (int t = 0; t < NT2; ++t) {
        const int kc = t * BKS;
        #pragma unroll
        for (int i = 0; i < 4; ++i)
            gload16(hsrc[i] + kc, (char*)HL + (wid*4 + i)*1024);
        #pragma unroll
        for (int i = 0; i < 4; ++i)
            gload16(wsrc[i] + kc, (char*)W2L + (wid*4 + i)*1024);
        __syncthreads();
        #pragma unroll
        for (int s = 0; s < 2; ++s) {
            bf16x8 a[4];
            #pragma unroll
            for (int fm = 0; fm < 4; ++fm) {
                const int rr = wm*64 + fm*16 + l15;
                a[fm] = *reinterpret_cast<const bf16x8*>(
                    (const char*)HL + rr*128 + (((s*4 + lg) ^ (rr & 7)) << 4));
            }
            bf16x8 bf[2];
            #pragma unroll
            for (int fn = 0; fn < 2; ++fn) {
                const int rw = wn*32 + fn*16 + l15;
                const char* p = (const char*)W2L + rw*256 + (((s*4 + lg) ^ (rw & 7)) << 5);
                bf[fn] = cvt8(*reinterpret_cast<const f32x4*>(p),
                              *reinterpret_cast<const f32x4*>(p + 16));
            }
            #pragma unroll
            for (int fm = 0; fm < 4; ++fm) {
                #pragma unroll
                for (int fn = 0; fn < 2; ++fn) {
                    acc[fm][fn] = __builtin_amdgcn_mfma_f32_16x16x32_bf16(a[fm], bf[fn], acc[fm][fn], 0, 0, 0);
                }
            }
        }
        __syncthreads();
    }

    #pragma unroll
    for (int fm = 0; fm < 4; ++fm) {
        #pragma unroll
        for (int fn = 0; fn < 2; ++fn) {
            const int col = htile*BN + wn*32 + fn*16 + l15;
            const float bv = B2[col];
            #pragma unroll
            for (int j = 0; j < 4; ++j) {
                const int rl = wm*64 + fm*16 + lg*4 + j;
                if (rl < rows) {
                    const float g = entry_gate[off + ro + rl];
                    ybuf[(size_t)(off+ro+rl)*H_ + col] = (acc[fm][fn][j] + bv) * g;
                }
            }
        }
    }
}

// ---------------------------------------------------------------------------
// Combine: out[t] = y_shared[t] + sum_k y_routed[pair_pos[t,k]]
// ---------------------------------------------------------------------------
__global__ __launch_bounds__(128) void moe_combine(
    const float* __restrict__ ybuf, const int* __restrict__ pair_pos,
    float* __restrict__ out)
{
    const int t = blockIdx.x;
    const int lane = threadIdx.x;     // 128 threads * 4 floats = 512
    const int h = lane * 4;
    const int p0 = pair_pos[t*K_+0], p1 = pair_pos[t*K_+1];
    const int p2 = pair_pos[t*K_+2], p3 = pair_pos[t*K_+3];
    float4 a  = *reinterpret_cast<const float4*>(ybuf + (size_t)(NPAIR+t)*H_ + h);
    float4 v0 = *reinterpret_cast<const float4*>(ybuf + (size_t)p0*H_ + h);
    float4 v1 = *reinterpret_cast<const float4*>(ybuf + (size_t)p1*H_ + h);
    float4 v2 = *reinterpret_cast<const float4*>(ybuf + (size_t)p2*H_ + h);
    float4 v3 = *reinterpret_cast<const float4*>(ybuf + (size_t)p3*H_ + h);
    float4 r;
    r.x = a.x + v0.x + v1.x + v2.x + v3.x;
    r.y = a.y + v0.y + v1.y + v2.y + v3.y;
    r.z = a.z + v0.z + v1.z + v2.z + v3.z;
    r.w = a.w + v0.w + v1.w + v2.w + v3.w;
    *reinterpret_cast<float4*>(out + (size_t)t*H_ + h) = r;
}

extern "C" void kernel_launch(void* const* d_in, const int* in_sizes, int n_in,
                              void* d_out, int out_size, void* d_ws, size_t ws_size,
                              hipStream_t stream)
{
    const float* x   = (const float*)d_in[0];
    const float* rw  = (const float*)d_in[1];
    const float* rb  = (const float*)d_in[2];
    const float* eb  = (const float*)d_in[3];
    const float* sw1 = (const float*)d_in[4];
    const float* sb1 = (const float*)d_in[5];
    const float* sw2 = (const float*)d_in[6];
    const float* sb2 = (const float*)d_in[7];
    const float* sw3 = (const float*)d_in[8];
    const float* sb3 = (const float*)d_in[9];
    const float* w1  = (const float*)d_in[10];
    const float* b1  = (const float*)d_in[11];
    const float* w2  = (const float*)d_in[12];
    const float* b2  = (const float*)d_in[13];
    const float* w3  = (const float*)d_in[14];
    const float* b3  = (const float*)d_in[15];
    float* out = (float*)d_out;

    char* p = (char*)d_ws;
    auto take = [&](size_t bytes) { char* q = p; p += (bytes + 255) & ~(size_t)255; return q; };
    int*    idxb  = (int*)   take((size_t)NPAIR*4);
    float*  gateb = (float*) take((size_t)NPAIR*4);
    int*    cnts  = (int*)   take((E_+1)*4);
    int*    offs  = (int*)   take((E_+1)*4);
    int*    etok  = (int*)   take((size_t)NENT*4);
    float*  egate = (float*) take((size_t)NENT*4);
    int*    ppos  = (int*)   take((size_t)NPAIR*4);
    int*    blk_e = (int*)   take((size_t)MAXWORK*4);
    int*    blk_ro= (int*)   take((size_t)MAXWORK*4);
    int*    nwork = (int*)   take(4);
    ushort* xg    = (ushort*)take((size_t)NENT*H_*2);
    ushort* h1buf = (ushort*)take((size_t)NENT*I_*2);
    float*  ybuf  = (float*) take((size_t)NENT*H_*4);

    moe_router <<<T_, 64, 0, stream>>>(x, rw, rb, eb, idxb, gateb);
    moe_build  <<<1, 256, 0, stream>>>(idxb, gateb, cnts, offs, etok, egate, ppos,
                                       blk_e, blk_ro, nwork);
    moe_xpack  <<<NENT, 128, 0, stream>>>(x, etok, xg);
    moe_stage1 <<<dim3(MAXWORK, I_/BN), 256, 0, stream>>>(xg, w1, b1, w3, b3,
                                                          sw1, sb1, sw3, sb3,
                                                          cnts, offs,
                                                          blk_e, blk_ro, nwork, h1buf);
    moe_stage2 <<<dim3(MAXWORK, H_/BN), 256, 0, stream>>>(h1buf, w2, b2, sw2, sb2,
                                                          cnts, offs, egate,
                                                          blk_e, blk_ro, nwork, ybuf);
    moe_combine<<<T_, 128, 0, stream>>>(ybuf, ppos, out);
}